// Round 6
// baseline (1086.913 us; speedup 1.0000x reference)
//
#include <hip/hip_runtime.h>
#include <cstdint>

#define NB 512   // batch
#define ND 128   // D
#define NW 256   // timesteps
#define NH 256   // hidden
#define SENT32 0x7C007C00u
#define SENT64 0x7C007C007C007C00ull

typedef _Float16 f16;
typedef _Float16 h8 __attribute__((ext_vector_type(8)));
typedef float f32x4 __attribute__((ext_vector_type(4)));
typedef unsigned long long u64;

__device__ __forceinline__ float sigm(float v){ return 1.f/(1.f+__expf(-v)); }
__device__ __forceinline__ float tanh_fast(float v){
  v = fminf(fmaxf(v,-15.f),15.f);
  float e = __expf(2.f*v);
  return (e-1.f)/(e+1.f);
}

// ---------------------------------------------------------------------------
// a[b,d] = softmax_d( x[b,d,:] . w_x + attn_b )   (h/c term cancels in softmax)
// ---------------------------------------------------------------------------
__global__ __launch_bounds__(128) void attn_kernel(
    const float* __restrict__ x, const float* __restrict__ attn_w,
    const float* __restrict__ attn_b, float* __restrict__ a_buf)
{
    __shared__ float wx[NW];
    __shared__ float sred[2];
    const int b = blockIdx.x;
    const int d = threadIdx.x;

    wx[d]       = attn_w[2 * NH + d];
    wx[d + 128] = attn_w[2 * NH + d + 128];
    __syncthreads();

    const float4* xr = (const float4*)(x + ((size_t)b * ND + d) * NW);
    float acc = 0.f;
    #pragma unroll 8
    for (int w4 = 0; w4 < NW / 4; ++w4) {
        float4 v = xr[w4];
        acc += v.x * wx[w4*4+0] + v.y * wx[w4*4+1]
             + v.z * wx[w4*4+2] + v.w * wx[w4*4+3];
    }
    float e = acc + attn_b[0];

    float mx = e;
    #pragma unroll
    for (int o = 32; o > 0; o >>= 1) mx = fmaxf(mx, __shfl_xor(mx, o));
    if ((d & 63) == 0) sred[d >> 6] = mx;
    __syncthreads();
    mx = fmaxf(sred[0], sred[1]);
    __syncthreads();

    float p = __expf(e - mx);
    float s = p;
    #pragma unroll
    for (int o = 32; o > 0; o >>= 1) s += __shfl_xor(s, o);
    if ((d & 63) == 0) sred[d >> 6] = s;
    __syncthreads();
    s = sred[0] + sred[1];

    a_buf[(size_t)b * ND + d] = p / s;
}

// ---------------------------------------------------------------------------
// Pack W_aug = [W_hh | W_ih] into per-(wq,ktile) MFMA B-fragments (fp16).
// wq = q*4 + w (16 q-blocks x 4 waves). B-frag (16x16x32): lane l holds
// B[k = kt*32 + (l>>4)*8 + e][col16 = l&15];
// col16 -> hcol = wq*4 + (col16>>2), gate = col16&3, n = gate*256 + hcol.
// ---------------------------------------------------------------------------
__global__ __launch_bounds__(512) void pack_kernel(
    const float* __restrict__ W_ih, const float* __restrict__ W_hh,
    const float* __restrict__ b_ih, const float* __restrict__ b_hh,
    f16* __restrict__ Wfrag, float* __restrict__ bias)
{
    int flat = blockIdx.x * 512 + threadIdx.x;   // 0..49151
    int l    = flat & 63;
    int kt   = (flat >> 6) % 12;
    int wq   = (flat >> 6) / 12;                 // 0..63 = q*4 + w
    int col16 = l & 15, kb = l >> 4;
    int hcol = wq * 4 + (col16 >> 2);
    int gate = col16 & 3;
    int n    = gate * 256 + hcol;
    int k0   = kt * 32 + kb * 8;

    f16 tmp[8];
    #pragma unroll
    for (int e = 0; e < 8; ++e) {
        int k = k0 + e;
        float v = (k < NH) ? W_hh[(size_t)n * NH + k]
                           : W_ih[(size_t)n * ND + (k - NH)];
        tmp[e] = (f16)v;
    }
    *(h8*)(Wfrag + (size_t)flat * 8) = *(const h8*)tmp;

    if (flat < 1024) bias[flat] = b_ih[flat] + b_hh[flat];
}

// poison all 8 slots of hx with fp16-inf sentinel (|h|<1 always)
__global__ __launch_bounds__(512) void poison_kernel(uint4* __restrict__ hx4)
{
    uint4 v = {SENT32, SENT32, SENT32, SENT32};
    hx4[(size_t)blockIdx.x * 512 + threadIdx.x] = v;   // 256 blocks -> 2 MB
}

// ---------------------------------------------------------------------------
// Persistent pipelined LSTM: 256 blocks (p2 = bid&15, q = bid>>4), 256 thr
// (4 waves). Block owns TWO independent 16-row chunks (rows p2*32 + C*16)
// and h-cols q*16..+16. Phases interleave A(t), B(t): each chunk's L3
// exchange round-trip is hidden under the other chunk's compute.
// Exchange = round-4 self-flagging protocol (proven): hx 8 slots poisoned
// with fp16-inf; producers store h relaxed/agent; consumers poll data u32s;
// slot (t+3)&7's own region re-poisoned each phase; per-phase vmcnt(0)
// orders poison < next data write. No XCD/coherence assumptions.
// ---------------------------------------------------------------------------
__global__ __launch_bounds__(256, 1) void lstm_kernel(
    const float* __restrict__ x, const float* __restrict__ a_buf,
    const float* __restrict__ bias, const f16* __restrict__ Wfrag,
    f16* __restrict__ hx, float* __restrict__ out)
{
    __shared__ __align__(16) unsigned char A16[2][16 * 768]; // [chunk][row][384 f16]
    __shared__ float scr[4][272];                            // per-wave 16x16 +pad

    const int tid = threadIdx.x;
    const int w = tid >> 6, l = tid & 63;
    const int p2 = blockIdx.x & 15, q = blockIdx.x >> 4;

    // --- weights -> registers (persistent): 12 kt x h8 = 48 VGPR ---
    h8 bfrag[12];
    {
        const h8* wsrc = (const h8*)Wfrag + ((q * 4 + w) * 12) * 64 + l;
        #pragma unroll
        for (int kt = 0; kt < 12; ++kt) bfrag[kt] = wsrc[kt * 64];
    }

    const int m = l >> 2, hh = l & 3;          // epilogue lane roles
    const int jcol = q * 16 + w * 4 + hh;
    float bias4[4];
    #pragma unroll
    for (int g = 0; g < 4; ++g) bias4[g] = bias[g * 256 + jcol];
    float cst0 = 0.f, cst1 = 0.f;              // per-chunk cell states

    // --- per-thread roles ---
    const int xrow = tid >> 4, xdc = tid & 15; // x loader: 16 rows x 16 dchunks
    const int r2 = tid >> 4, kc = tid & 15;    // h stage: 16 rows x 16 x 32B
    const int arow = l & 15, akb = l >> 4;     // A-frag read role
    const int pr = tid >> 2, pc = tid & 3;     // poison role (tid<64)

    float areg0[8], areg1[8];
    const float* xbase0 = x + ((size_t)(p2 * 32 + xrow) * ND + xdc * 8) * NW;
    const float* xbase1 = x + ((size_t)(p2 * 32 + 16 + xrow) * ND + xdc * 8) * NW;
    #pragma unroll
    for (int e = 0; e < 8; ++e) {
        areg0[e] = a_buf[(p2 * 32 + xrow) * ND + xdc * 8 + e];
        areg1[e] = a_buf[(p2 * 32 + 16 + xrow) * ND + xdc * 8 + e];
    }
    float4 xq0[8], xq1[8];

    // --- prologue: zero h-regions of both chunks (h0 = 0) ---
    {
        h8 z = {};
        #pragma unroll
        for (int c = 0; c < 2; ++c) {
            int byte = c * 12288 + r2 * 768 + kc * 32;
            *(h8*)(A16[0] + (byte ^ ((r2 & 7) << 4))) = z;
            *(h8*)(A16[0] + ((byte + 16) ^ ((r2 & 7) << 4))) = z;
        }
    }
    __syncthreads();

    // ---- one pipeline phase for chunk C at step t ----
    #define PHASE(C, CST, XQ, AREG, XBASE)                                        \
    do {                                                                          \
        /* refill 4-step x register cache */                                      \
        if ((t & 3) == 0) {                                                       \
            _Pragma("unroll")                                                     \
            for (int e = 0; e < 8; ++e)                                           \
                XQ[e] = *(const float4*)(XBASE + (size_t)e * NW + t);             \
        }                                                                         \
        /* stage a*x_t -> A16[C] x-region (rotate keeps indexing static) */       \
        {                                                                         \
            f16 xv[8];                                                            \
            _Pragma("unroll")                                                     \
            for (int e = 0; e < 8; ++e) {                                         \
                float xf = XQ[e].x;                                               \
                XQ[e] = make_float4(XQ[e].y, XQ[e].z, XQ[e].w, XQ[e].x);          \
                xv[e] = (f16)(xf * AREG[e]);                                      \
            }                                                                     \
            int byte = (C) * 12288 + xrow * 768 + 512 + xdc * 16;                 \
            byte ^= (xrow & 7) << 4;                                              \
            *(h8*)(A16[0] + byte) = *(const h8*)xv;                               \
        }                                                                         \
        /* poll self-flagging h_{t-1}, land into A16[C] h-region */               \
        if (t > 0) {                                                              \
            const u64* hrow = (const u64*)                                        \
                (hx + ((size_t)((t - 1) & 7) * NB + p2 * 32 + (C) * 16 + r2) * NH); \
            u64 d0, d1, d2, d3;                                                   \
            for (;;) {                                                            \
                d0 = __hip_atomic_load(hrow + kc * 4 + 0,                         \
                        __ATOMIC_RELAXED, __HIP_MEMORY_SCOPE_AGENT);              \
                d1 = __hip_atomic_load(hrow + kc * 4 + 1,                         \
                        __ATOMIC_RELAXED, __HIP_MEMORY_SCOPE_AGENT);              \
                d2 = __hip_atomic_load(hrow + kc * 4 + 2,                         \
                        __ATOMIC_RELAXED, __HIP_MEMORY_SCOPE_AGENT);              \
                d3 = __hip_atomic_load(hrow + kc * 4 + 3,                         \
                        __ATOMIC_RELAXED, __HIP_MEMORY_SCOPE_AGENT);              \
                if ((unsigned)d0 != SENT32 && (unsigned)(d0 >> 32) != SENT32 &&   \
                    (unsigned)d1 != SENT32 && (unsigned)(d1 >> 32) != SENT32 &&   \
                    (unsigned)d2 != SENT32 && (unsigned)(d2 >> 32) != SENT32 &&   \
                    (unsigned)d3 != SENT32 && (unsigned)(d3 >> 32) != SENT32) break; \
                __builtin_amdgcn_s_sleep(1);                                      \
            }                                                                     \
            int byte = (C) * 12288 + r2 * 768 + kc * 32;                          \
            int b0 = byte ^ ((r2 & 7) << 4);                                      \
            int b1 = (byte + 16) ^ ((r2 & 7) << 4);                               \
            ((u64*)(A16[0] + b0))[0] = d0; ((u64*)(A16[0] + b0))[1] = d1;         \
            ((u64*)(A16[0] + b1))[0] = d2; ((u64*)(A16[0] + b1))[1] = d3;         \
        }                                                                         \
        __syncthreads();   /* A16[C] ready */                                     \
        /* 12x MFMA: gates[16 x col16] for this wave's N-tile */                  \
        f32x4 acc = {0.f, 0.f, 0.f, 0.f};                                         \
        _Pragma("unroll")                                                         \
        for (int kt = 0; kt < 12; ++kt) {                                         \
            int byte = (C) * 12288 + arow * 768 + kt * 64 + akb * 16;             \
            byte ^= (arow & 7) << 4;                                              \
            h8 afrag = *(const h8*)(A16[0] + byte);                               \
            acc = __builtin_amdgcn_mfma_f32_16x16x32_f16(afrag, bfrag[kt], acc, 0, 0, 0); \
        }                                                                         \
        /* epilogue: gate transpose via per-wave LDS, LSTM cell */                \
        float hn;                                                                 \
        {                                                                         \
            float* sw = &scr[w][0];                                               \
            int col = l & 15, rb = (l >> 4) * 4;                                  \
            sw[(rb + 0) * 17 + col] = acc[0];                                     \
            sw[(rb + 1) * 17 + col] = acc[1];                                     \
            sw[(rb + 2) * 17 + col] = acc[2];                                     \
            sw[(rb + 3) * 17 + col] = acc[3];                                     \
            asm volatile("s_waitcnt lgkmcnt(0)" ::: "memory");                    \
            float G0 = sw[m * 17 + hh * 4 + 0] + bias4[0];                        \
            float G1 = sw[m * 17 + hh * 4 + 1] + bias4[1];                        \
            float G2 = sw[m * 17 + hh * 4 + 2] + bias4[2];                        \
            float G3 = sw[m * 17 + hh * 4 + 3] + bias4[3];                        \
            float ig = sigm(G0), fg = sigm(G1);                                   \
            float gg = tanh_fast(G2), og = sigm(G3);                              \
            CST = fg * CST + ig * gg;                                             \
            hn = og * tanh_fast(CST);                                             \
        }                                                                         \
        /* publish h immediately (the only thing consumers wait on) */            \
        {                                                                         \
            f16 hf = (f16)hn;                                                     \
            unsigned short hb = __builtin_bit_cast(unsigned short, hf);           \
            int other = __shfl_xor((int)hb, 1);                                   \
            if (!(l & 1)) {                                                       \
                unsigned val = (unsigned)hb | ((unsigned)(unsigned short)other << 16); \
                unsigned* dst = (unsigned*)((unsigned short*)hx                   \
                    + ((size_t)(t & 7) * NB + p2 * 32 + (C) * 16 + m) * NH + jcol); \
                __hip_atomic_store(dst, val,                                      \
                        __ATOMIC_RELAXED, __HIP_MEMORY_SCOPE_AGENT);              \
            }                                                                     \
        }                                                                         \
        out[((size_t)(p2 * 32 + (C) * 16 + m) * NW + t) * NH + jcol] = hn;        \
        /* re-poison own region of slot (t+3)&7 (holds h(t-5), consumed) */       \
        if (tid < 64) {                                                           \
            u64* pb = (u64*)((unsigned short*)hx                                  \
                + ((size_t)((t + 3) & 7) * NB + p2 * 32 + (C) * 16 + pr) * NH     \
                + q * 16 + pc * 4);                                               \
            __hip_atomic_store(pb, SENT64,                                        \
                    __ATOMIC_RELAXED, __HIP_MEMORY_SCOPE_AGENT);                  \
        }                                                                         \
        /* drain: orders poison/publish for the 3-step-later slot reuse */        \
        asm volatile("s_waitcnt vmcnt(0)" ::: "memory");                          \
        __syncthreads();                                                          \
    } while (0)

    for (int t = 0; t < NW; ++t) {
        PHASE(0, cst0, xq0, areg0, xbase0);
        PHASE(1, cst1, xq1, areg1, xbase1);
    }
    #undef PHASE
}

// ---------------------------------------------------------------------------
extern "C" void kernel_launch(void* const* d_in, const int* in_sizes, int n_in,
                              void* d_out, int out_size, void* d_ws, size_t ws_size,
                              hipStream_t stream) {
    (void)in_sizes; (void)n_in; (void)out_size;

    const float* x      = (const float*)d_in[0];
    const float* attn_w = (const float*)d_in[1];
    const float* attn_b = (const float*)d_in[2];
    const float* W_ih   = (const float*)d_in[3];
    const float* W_hh   = (const float*)d_in[4];
    const float* b_ih   = (const float*)d_in[5];
    const float* b_hh   = (const float*)d_in[6];
    float* out = (float*)d_out;

    char* ws = (char*)d_ws;
    float* a_buf = (float*)ws;                 // 256 KiB
    float* bias  = (float*)(ws + 262144);      //   4 KiB
    f16*   Wfrag = (f16*)(ws + 266240);        // 768 KiB
    f16*   hx    = (f16*)(ws + 1052672);       //   2 MiB (8 slots)
    if (ws_size < (size_t)3149824) return;

    attn_kernel<<<NB, 128, 0, stream>>>(x, attn_w, attn_b, a_buf);
    pack_kernel<<<96, 512, 0, stream>>>(W_ih, W_hh, b_ih, b_hh, Wfrag, bias);
    poison_kernel<<<256, 512, 0, stream>>>((uint4*)hx);
    lstm_kernel<<<256, 256, 0, stream>>>(x, a_buf, bias, Wfrag, hx, out);
}

// Round 7
// 1005.820 us; speedup vs baseline: 1.0806x; 1.0806x over previous
//
#include <hip/hip_runtime.h>
#include <cstdint>

#define NB 512   // batch
#define ND 128   // D
#define NW 256   // timesteps
#define NH 256   // hidden
#define SENT32 0x7C007C00u
#define SENT64 0x7C007C007C007C00ull

typedef _Float16 f16;
typedef _Float16 h4 __attribute__((ext_vector_type(4)));
typedef _Float16 h8 __attribute__((ext_vector_type(8)));
typedef float f32x4 __attribute__((ext_vector_type(4)));
typedef unsigned long long u64;

__device__ __forceinline__ float sigm(float v){ return 1.f/(1.f+__expf(-v)); }
__device__ __forceinline__ float tanh_fast(float v){
  v = fminf(fmaxf(v,-15.f),15.f);
  float e = __expf(2.f*v);
  return (e-1.f)/(e+1.f);
}

// ---------------------------------------------------------------------------
// a[b,d] = softmax_d( x[b,d,:] . w_x + attn_b )   (h/c term cancels in softmax)
// ---------------------------------------------------------------------------
__global__ __launch_bounds__(128) void attn_kernel(
    const float* __restrict__ x, const float* __restrict__ attn_w,
    const float* __restrict__ attn_b, float* __restrict__ a_buf)
{
    __shared__ float wx[NW];
    __shared__ float sred[2];
    const int b = blockIdx.x;
    const int d = threadIdx.x;

    wx[d]       = attn_w[2 * NH + d];
    wx[d + 128] = attn_w[2 * NH + d + 128];
    __syncthreads();

    const float4* xr = (const float4*)(x + ((size_t)b * ND + d) * NW);
    float acc = 0.f;
    #pragma unroll 8
    for (int w4 = 0; w4 < NW / 4; ++w4) {
        float4 v = xr[w4];
        acc += v.x * wx[w4*4+0] + v.y * wx[w4*4+1]
             + v.z * wx[w4*4+2] + v.w * wx[w4*4+3];
    }
    float e = acc + attn_b[0];

    float mx = e;
    #pragma unroll
    for (int o = 32; o > 0; o >>= 1) mx = fmaxf(mx, __shfl_xor(mx, o));
    if ((d & 63) == 0) sred[d >> 6] = mx;
    __syncthreads();
    mx = fmaxf(sred[0], sred[1]);
    __syncthreads();

    float p = __expf(e - mx);
    float s = p;
    #pragma unroll
    for (int o = 32; o > 0; o >>= 1) s += __shfl_xor(s, o);
    if ((d & 63) == 0) sred[d >> 6] = s;
    __syncthreads();
    s = sred[0] + sred[1];

    a_buf[(size_t)b * ND + d] = p / s;
}

// ---------------------------------------------------------------------------
// Pack W into per-(tau,kt) MFMA B-fragments, K-order block-local:
// tile tau 0..63 (16 gate-cols each), H = tau>>5 (owner block half).
// k<128: own half h  = h[H*128+k];  k in [128,256): partner half;
// k>=256: x (d = k-256).  B-frag 16x16x32: lane l holds
// B[k = kt*32 + (l>>4)*8 + e][col16 = l&15]; j = tau*4 + (col16>>2),
// gate = col16&3, weight row n = gate*256 + j.
// ---------------------------------------------------------------------------
__global__ __launch_bounds__(512) void pack_kernel(
    const float* __restrict__ W_ih, const float* __restrict__ W_hh,
    const float* __restrict__ b_ih, const float* __restrict__ b_hh,
    f16* __restrict__ Wfrag, float* __restrict__ bias)
{
    int flat = blockIdx.x * 512 + threadIdx.x;   // 0..49151
    int l    = flat & 63;
    int kt   = (flat >> 6) % 12;
    int tau  = (flat >> 6) / 12;                 // 0..63
    int H    = tau >> 5;
    int c2   = (l & 15) >> 2, gate = l & 3;
    int j    = tau * 4 + c2;
    int n    = gate * 256 + j;
    int k0   = kt * 32 + (l >> 4) * 8;

    f16 tmp[8];
    #pragma unroll
    for (int e = 0; e < 8; ++e) {
        int k = k0 + e;
        float v;
        if (k < 128)      v = W_hh[(size_t)n * NH + H * 128 + k];
        else if (k < 256) v = W_hh[(size_t)n * NH + (1 - H) * 128 + (k - 128)];
        else              v = W_ih[(size_t)n * ND + (k - 256)];
        tmp[e] = (f16)v;
    }
    *(h8*)(Wfrag + (size_t)flat * 8) = *(const h8*)tmp;

    if (flat < 1024) bias[flat] = b_ih[flat] + b_hh[flat];
}

// poison all 8 hx slots with fp16-inf sentinel (|h|<1 always)
__global__ __launch_bounds__(512) void poison_kernel(uint4* __restrict__ hx4)
{
    uint4 v = {SENT32, SENT32, SENT32, SENT32};
    hx4[(size_t)blockIdx.x * 512 + threadIdx.x] = v;   // 256 blocks -> 2 MB
}

// ---------------------------------------------------------------------------
// Persistent 2-party LSTM: 64 blocks (g = bid>>1, H = bid&1), 512 threads
// (8 waves). Block (g,H): batch rows g*16..+16, h-cols H*128..+128
// (512 gate-cols = 32 tiles; wave w owns tiles tau = H*32+w*4+n, n 0..3).
// Weights: W_hh own+partner K-halves in VGPR (128/lane); W_ih x-part in LDS
// (128 KB). h own-half feeds back via LDS only; partner half via the proven
// self-flagging hx protocol (fp16-inf poison, relaxed agent atomics,
// poison-lead-3, per-step vmcnt(0) BEFORE the out-store).
// LDS (dynamic, 148.5 KB): wx[0,128K) | A16 16x768B | scr 8x272 f32.
// ---------------------------------------------------------------------------
__global__ __launch_bounds__(512, 2) void lstm_kernel(
    const float* __restrict__ x, const float* __restrict__ a_buf,
    const float* __restrict__ bias, const f16* __restrict__ Wfrag,
    f16* __restrict__ hx, float* __restrict__ out)
{
    extern __shared__ __align__(16) char smem[];
    f16* wx = (f16*)smem;                                   // 131072 B
    unsigned char* A16 = (unsigned char*)smem + 131072;     //  12288 B
    float* scr = (float*)(smem + 143360);                   //   8704 B

    const int tid = threadIdx.x;
    const int w = tid >> 6, l = tid & 63;
    const int g = blockIdx.x >> 1, H = blockIdx.x & 1;
    const int b0 = g * 16;

    // --- weights: own/partner h-halves -> VGPR; x-part -> LDS fragments ---
    h8 bh[4][4], bp[4][4];
    #pragma unroll
    for (int n = 0; n < 4; ++n) {
        const int tau = H * 32 + w * 4 + n;
        const h8* base = (const h8*)Wfrag + (size_t)tau * 12 * 64 + l;
        #pragma unroll
        for (int ktl = 0; ktl < 4; ++ktl) bh[n][ktl] = base[ktl * 64];
        #pragma unroll
        for (int ktl = 0; ktl < 4; ++ktl) bp[n][ktl] = base[(4 + ktl) * 64];
        #pragma unroll
        for (int ktl = 0; ktl < 4; ++ktl) {
            h8 v = base[(8 + ktl) * 64];
            *(h8*)(wx + ((size_t)(w * 16 + n * 4 + ktl) * 64 + l) * 8) = v;
        }
    }

    const int m = l >> 2, hh = l & 3;          // epilogue lane roles
    float biasv[4][4];                          // [tile][gate]
    #pragma unroll
    for (int n = 0; n < 4; ++n)
        #pragma unroll
        for (int gate = 0; gate < 4; ++gate)
            biasv[n][gate] = bias[gate * 256 + H * 128 + w * 16 + n * 4 + hh];
    float cstate[4] = {0.f, 0.f, 0.f, 0.f};

    // --- roles ---
    const int xrow = tid >> 5, xdc2 = tid & 31;  // x loader: 16 rows x 32 (4d)
    const int pr = tid >> 4, pc = tid & 15;      // poller (tid<256): row, 16B-chunk
    const int arow = l & 15, akb = l >> 4;       // A-frag read role

    float areg[4];
    const float* xbase = x + ((size_t)(b0 + xrow) * ND + xdc2 * 4) * NW;
    #pragma unroll
    for (int e = 0; e < 4; ++e)
        areg[e] = a_buf[(b0 + xrow) * ND + xdc2 * 4 + e];
    float4 xq[4];

    // hx region offsets (u64 units; one region = 16 rows x 128 f16 = 512 u64)
    #define REG_OFF_U64(slot, half) \
        ((size_t)(((slot) * 32 + g) * 2 + (half)) * 512)

    // --- prologue: zero own+partner h regions; stage x_hat(0) ---
    {
        int byte = (tid >> 5) * 768 + (tid & 31) * 16;
        byte ^= ((tid >> 5) & 7) << 4;
        h8 z = {};
        *(h8*)(A16 + byte) = z;
    }
    #pragma unroll
    for (int e = 0; e < 4; ++e)
        xq[e] = *(const float4*)(xbase + (size_t)e * NW);
    {
        f16 xv[4];
        #pragma unroll
        for (int e = 0; e < 4; ++e) {
            float xf = xq[e].x;
            xq[e] = make_float4(xq[e].y, xq[e].z, xq[e].w, xq[e].x);
            xv[e] = (f16)(xf * areg[e]);
        }
        int byte = xrow * 768 + 512 + xdc2 * 8;
        byte ^= (xrow & 7) << 4;
        *(h4*)(A16 + byte) = *(const h4*)xv;
    }
    __syncthreads();

    for (int t = 0; t < NW; ++t) {
        // --- pollers: poison slot (t+3) of the region we READ; issue probe ---
        u64 d0 = 0, d1 = 0;
        const u64* src = nullptr;
        if (tid < 256) {
            u64* pb = (u64*)hx + REG_OFF_U64((t + 3) & 7, 1 - H) + pr * 32 + pc * 2;
            __hip_atomic_store(pb + 0, SENT64, __ATOMIC_RELAXED, __HIP_MEMORY_SCOPE_AGENT);
            __hip_atomic_store(pb + 1, SENT64, __ATOMIC_RELAXED, __HIP_MEMORY_SCOPE_AGENT);
            if (t > 0) {
                src = (const u64*)hx + REG_OFF_U64((t - 1) & 7, 1 - H) + pr * 32 + pc * 2;
                d0 = __hip_atomic_load(src + 0, __ATOMIC_RELAXED, __HIP_MEMORY_SCOPE_AGENT);
                d1 = __hip_atomic_load(src + 1, __ATOMIC_RELAXED, __HIP_MEMORY_SCOPE_AGENT);
            }
        }

        // --- pre-barrier MFMA: own-h (VGPR B) + x (LDS B), poll in flight ---
        f32x4 acc[4] = {{0.f,0.f,0.f,0.f},{0.f,0.f,0.f,0.f},
                        {0.f,0.f,0.f,0.f},{0.f,0.f,0.f,0.f}};
        #pragma unroll
        for (int ktl = 0; ktl < 4; ++ktl) {
            int byte = arow * 768 + ktl * 64 + akb * 16;
            byte ^= (arow & 7) << 4;
            h8 afrag = *(const h8*)(A16 + byte);
            #pragma unroll
            for (int n = 0; n < 4; ++n)
                acc[n] = __builtin_amdgcn_mfma_f32_16x16x32_f16(afrag, bh[n][ktl], acc[n], 0, 0, 0);
        }
        #pragma unroll
        for (int ktl = 0; ktl < 4; ++ktl) {
            int byte = arow * 768 + (8 + ktl) * 64 + akb * 16;
            byte ^= (arow & 7) << 4;
            h8 afrag = *(const h8*)(A16 + byte);
            #pragma unroll
            for (int n = 0; n < 4; ++n) {
                h8 bx = *(const h8*)(wx + ((size_t)(w * 16 + n * 4 + ktl) * 64 + l) * 8);
                acc[n] = __builtin_amdgcn_mfma_f32_16x16x32_f16(afrag, bx, acc[n], 0, 0, 0);
            }
        }

        // --- complete the poll, land partner half into LDS ---
        if (t > 0 && tid < 256) {
            for (;;) {
                if ((unsigned)d0 != SENT32 && (unsigned)(d0 >> 32) != SENT32 &&
                    (unsigned)d1 != SENT32 && (unsigned)(d1 >> 32) != SENT32) break;
                __builtin_amdgcn_s_sleep(2);
                d0 = __hip_atomic_load(src + 0, __ATOMIC_RELAXED, __HIP_MEMORY_SCOPE_AGENT);
                d1 = __hip_atomic_load(src + 1, __ATOMIC_RELAXED, __HIP_MEMORY_SCOPE_AGENT);
            }
            int byte = pr * 768 + 256 + pc * 16;
            byte ^= (pr & 7) << 4;
            ((u64*)(A16 + byte))[0] = d0;
            ((u64*)(A16 + byte))[1] = d1;
        }
        __syncthreads();   // partner region ready

        // --- partner-h MFMA (kt 4..7) ---
        #pragma unroll
        for (int ktl = 0; ktl < 4; ++ktl) {
            int byte = arow * 768 + (4 + ktl) * 64 + akb * 16;
            byte ^= (arow & 7) << 4;
            h8 afrag = *(const h8*)(A16 + byte);
            #pragma unroll
            for (int n = 0; n < 4; ++n)
                acc[n] = __builtin_amdgcn_mfma_f32_16x16x32_f16(afrag, bp[n][ktl], acc[n], 0, 0, 0);
        }

        // --- epilogue per tile: gate transpose, LSTM cell, publish ---
        float hn[4];
        float* sw = scr + w * 272;
        const int col = l & 15, rb = (l >> 4) * 4;
        #pragma unroll
        for (int n = 0; n < 4; ++n) {
            sw[(rb + 0) * 17 + col] = acc[n][0];
            sw[(rb + 1) * 17 + col] = acc[n][1];
            sw[(rb + 2) * 17 + col] = acc[n][2];
            sw[(rb + 3) * 17 + col] = acc[n][3];
            asm volatile("s_waitcnt lgkmcnt(0)" ::: "memory");
            float G0 = sw[m * 17 + hh * 4 + 0] + biasv[n][0];
            float G1 = sw[m * 17 + hh * 4 + 1] + biasv[n][1];
            float G2 = sw[m * 17 + hh * 4 + 2] + biasv[n][2];
            float G3 = sw[m * 17 + hh * 4 + 3] + biasv[n][3];
            float ig = sigm(G0), fg = sigm(G1);
            float gg = tanh_fast(G2), og = sigm(G3);
            cstate[n] = fg * cstate[n] + ig * gg;
            hn[n] = og * tanh_fast(cstate[n]);

            const int jl = w * 16 + n * 4 + hh;   // block-local h col
            // own-half feedback -> LDS (read next step, after end barrier)
            {
                int byte = m * 768 + jl * 2;
                byte ^= (m & 7) << 4;
                *(f16*)(A16 + byte) = (f16)hn[n];
            }
            // publish to partner (agent scope, self-flagging)
            f16 hf = (f16)hn[n];
            unsigned short hb = __builtin_bit_cast(unsigned short, hf);
            int other = __shfl_xor((int)hb, 1);
            if (!(l & 1)) {
                unsigned val = (unsigned)hb | ((unsigned)(unsigned short)other << 16);
                unsigned* dst = (unsigned*)hx + REG_OFF_U64(t & 7, H) * 2
                              + m * 64 + (jl >> 1);
                __hip_atomic_store(dst, val, __ATOMIC_RELAXED, __HIP_MEMORY_SCOPE_AGENT);
            }
        }

        // ack publish + poison (NOT the out-store) -> 3-step poison ordering
        asm volatile("s_waitcnt vmcnt(0)" ::: "memory");

        // out stores fly across the barrier; next step's drain reaps them
        #pragma unroll
        for (int n = 0; n < 4; ++n)
            out[((size_t)(b0 + m) * NW + t) * NH + H * 128 + w * 16 + n * 4 + hh] = hn[n];

        // stage x_hat(t+1)
        if (t + 1 < NW) {
            if (((t + 1) & 3) == 0) {
                #pragma unroll
                for (int e = 0; e < 4; ++e)
                    xq[e] = *(const float4*)(xbase + (size_t)e * NW + (t + 1));
            }
            f16 xv[4];
            #pragma unroll
            for (int e = 0; e < 4; ++e) {
                float xf = xq[e].x;
                xq[e] = make_float4(xq[e].y, xq[e].z, xq[e].w, xq[e].x);
                xv[e] = (f16)(xf * areg[e]);
            }
            int byte = xrow * 768 + 512 + xdc2 * 8;
            byte ^= (xrow & 7) << 4;
            *(h4*)(A16 + byte) = *(const h4*)xv;
        }
        __syncthreads();
    }
    #undef REG_OFF_U64
}

// ---------------------------------------------------------------------------
extern "C" void kernel_launch(void* const* d_in, const int* in_sizes, int n_in,
                              void* d_out, int out_size, void* d_ws, size_t ws_size,
                              hipStream_t stream) {
    (void)in_sizes; (void)n_in; (void)out_size;

    const float* x      = (const float*)d_in[0];
    const float* attn_w = (const float*)d_in[1];
    const float* attn_b = (const float*)d_in[2];
    const float* W_ih   = (const float*)d_in[3];
    const float* W_hh   = (const float*)d_in[4];
    const float* b_ih   = (const float*)d_in[5];
    const float* b_hh   = (const float*)d_in[6];
    float* out = (float*)d_out;

    char* ws = (char*)d_ws;
    float* a_buf = (float*)ws;                 // 256 KiB
    float* bias  = (float*)(ws + 262144);      //   4 KiB
    f16*   Wfrag = (f16*)(ws + 266240);        // 768 KiB
    f16*   hx    = (f16*)(ws + 1052672);       //   2 MiB (8 slots)
    if (ws_size < (size_t)3149824) return;

    const int smem_bytes = 152064;             // 128K wx + 12K A16 + 8.5K scr
    hipFuncSetAttribute((const void*)lstm_kernel,
                        hipFuncAttributeMaxDynamicSharedMemorySize, smem_bytes);

    attn_kernel<<<NB, 128, 0, stream>>>(x, attn_w, attn_b, a_buf);
    pack_kernel<<<96, 512, 0, stream>>>(W_ih, W_hh, b_ih, b_hh, Wfrag, bias);
    poison_kernel<<<256, 512, 0, stream>>>((uint4*)hx);
    lstm_kernel<<<64, 512, smem_bytes, stream>>>(x, a_buf, bias, Wfrag, hx, out);
}